// Round 6
// baseline (29.496 us; speedup 1.0000x reference)
//
#include <hip/hip_runtime.h>
#include <stdint.h>

// Problem constants (from reference)
#define PAD_LEN 64
#define DD      128
#define N_ITEMS 4096          // BSZ * N
#define VOCAB   50000
#define NSLICE  8             // = number of XCDs
#define SLICE_ROWS 6250       // ceil(VOCAB / NSLICE); slice = tok / 6250 in [0,7]

// ---------------------------------------------------------------------------
// Kernel A: per-(slice,item) partial sums.
//   slice = blockIdx % 8  -> with round-robin block->XCD dispatch, all blocks
//   of slice s land on XCD s, so emb rows [s*6250, (s+1)*6250) (3.2 MB f32)
//   become L2-resident there; all ~5x reuse of each row is served by L2.
//   One wave per (slice,item): ballot-compact the in-slice slots (~8 of 64),
//   gather those rows (lane l holds float2 cols [2l,2l+1]; one wave instr =
//   one full 512B row), accumulate, store partial[slice][item][128].
// ---------------------------------------------------------------------------
__global__ __launch_bounds__(256) void partial_kernel(
    const int*   __restrict__ ids,      // [N_ITEMS]
    const int*   __restrict__ tokens,   // [N_I, PAD_LEN]
    const float* __restrict__ emb,      // [VOCAB, DD] f32
    float*       __restrict__ partial)  // [NSLICE, N_ITEMS, DD] in ws
{
    const int lane  = threadIdx.x & 63;
    const int wave  = threadIdx.x >> 6;                 // 0..3
    const int slice = blockIdx.x & (NSLICE - 1);        // -> XCD (round-robin)
    const int item  = (blockIdx.x >> 3) * 4 + wave;     // 0..4095

    const int id  = ids[item];                          // wave-uniform
    const int tok = tokens[id * PAD_LEN + lane];        // all 64 slots, one load

    const int myslice = (int)((unsigned)tok / SLICE_ROWS);
    unsigned long long m = __ballot(myslice == slice);  // wave-uniform mask

    float ax = 0.f, ay = 0.f, bx = 0.f, by = 0.f;

    // two independent gathers in flight per trip
    while (m) {
        const int j0 = __ffsll(m) - 1;
        m &= m - 1;
        if (m) {
            const int j1 = __ffsll(m) - 1;
            m &= m - 1;
            const int t0 = __shfl(tok, j0, 64);
            const int t1 = __shfl(tok, j1, 64);
            const float2 e0 = *reinterpret_cast<const float2*>(
                emb + (size_t)t0 * DD + lane * 2);
            const float2 e1 = *reinterpret_cast<const float2*>(
                emb + (size_t)t1 * DD + lane * 2);
            ax += e0.x; ay += e0.y;
            bx += e1.x; by += e1.y;
        } else {
            const int t0 = __shfl(tok, j0, 64);
            const float2 e0 = *reinterpret_cast<const float2*>(
                emb + (size_t)t0 * DD + lane * 2);
            ax += e0.x; ay += e0.y;
        }
    }

    float2 r;
    r.x = ax + bx;
    r.y = ay + by;
    *reinterpret_cast<float2*>(
        partial + ((size_t)slice * N_ITEMS + item) * DD + lane * 2) = r;
}

// ---------------------------------------------------------------------------
// Kernel B: out[item] = (sum_s partial[s][item]) / len[item]
// One wave per item; lane holds float2. 16 MB read + 2 MB write, streaming.
// ---------------------------------------------------------------------------
__global__ __launch_bounds__(256) void reduce_kernel(
    const int*   __restrict__ ids,
    const float* __restrict__ lens,
    const float* __restrict__ partial,  // [NSLICE, N_ITEMS, DD]
    float*       __restrict__ out)      // [N_ITEMS, DD]
{
    const int gid  = blockIdx.x * 256 + threadIdx.x;    // 0..262143
    const int item = gid >> 6;
    const int lane = gid & 63;

    const int   id      = ids[item];                    // wave-uniform
    const float inv_len = 1.0f / lens[id];

    const float* p = partial + (size_t)item * DD + lane * 2;
    float ax = 0.f, ay = 0.f;
    #pragma unroll
    for (int s = 0; s < NSLICE; ++s) {
        const float2 e = *reinterpret_cast<const float2*>(
            p + (size_t)s * N_ITEMS * DD);
        ax += e.x; ay += e.y;
    }

    float2 r;
    r.x = ax * inv_len;
    r.y = ay * inv_len;
    *reinterpret_cast<float2*>(out + (size_t)item * DD + lane * 2) = r;
}

// ---------------------------------------------------------------------------
// Fallback (ws too small): f32 gather, one wave per item, float2 lanes (R1).
// ---------------------------------------------------------------------------
__global__ __launch_bounds__(256) void avg_gather_f32_kernel(
    const int*   __restrict__ ids,
    const int*   __restrict__ tokens,
    const float* __restrict__ lens,
    const float* __restrict__ emb,
    float*       __restrict__ out)
{
    const int lane = threadIdx.x & 63;
    const int wave = threadIdx.x >> 6;
    const int item = blockIdx.x * 4 + wave;

    const int   id      = ids[item];
    const float inv_len = 1.0f / lens[id];
    const int*  trow    = tokens + id * PAD_LEN;

    float accx = 0.0f, accy = 0.0f;
    #pragma unroll 8
    for (int k = 0; k < PAD_LEN; ++k) {
        const int t = trow[k];
        const float2 e =
            *reinterpret_cast<const float2*>(emb + (size_t)t * DD + lane * 2);
        accx += e.x;
        accy += e.y;
    }
    float2 r;
    r.x = accx * inv_len;
    r.y = accy * inv_len;
    *reinterpret_cast<float2*>(out + (size_t)item * DD + lane * 2) = r;
}

extern "C" void kernel_launch(void* const* d_in, const int* in_sizes, int n_in,
                              void* d_out, int out_size, void* d_ws, size_t ws_size,
                              hipStream_t stream) {
    const int*   ids    = (const int*)  d_in[0];
    const int*   tokens = (const int*)  d_in[1];
    const float* lens   = (const float*)d_in[2];
    const float* emb    = (const float*)d_in[3];
    float*       out    = (float*)d_out;

    const size_t need = (size_t)NSLICE * N_ITEMS * DD * sizeof(float); // 16 MB

    if (ws_size >= need) {
        float* partial = (float*)d_ws;
        // A: 8 slices x 4096 items, 4 items (waves) per block -> 8192 blocks
        partial_kernel<<<NSLICE * (N_ITEMS / 4), 256, 0, stream>>>(
            ids, tokens, emb, partial);
        // B: one wave per item -> 1024 blocks
        reduce_kernel<<<(N_ITEMS * 64) / 256, 256, 0, stream>>>(
            ids, lens, partial, out);
    } else {
        avg_gather_f32_kernel<<<N_ITEMS / 4, 256, 0, stream>>>(
            ids, tokens, lens, emb, out);
    }
}

// Round 7
// 22.418 us; speedup vs baseline: 1.3158x; 1.3158x over previous
//
#include <hip/hip_runtime.h>
#include <stdint.h>

// Problem constants (from reference)
#define PAD_LEN 64
#define DD      128
#define N_ITEMS 4096    // BSZ * N
#define VOCAB   50000
#define N4      (VOCAB * DD / 4)   // 1.6M float4 in the f32 table

// ---------------------------------------------------------------------------
// Pre-pass: f32 table -> bf16 (RNE) into ws. Each thread: 2 float4 (32B read,
// 16B write). 800k threads = 3125 blocks x 256, exactly one pass.
// ---------------------------------------------------------------------------
__global__ __launch_bounds__(256) void cvt_bf16_kernel(
    const float4* __restrict__ src,
    ushort4*      __restrict__ dst)
{
    const int t = blockIdx.x * 256 + threadIdx.x;   // 0..799999
    #pragma unroll
    for (int k = 0; k < 2; ++k) {
        const int i = 2 * t + k;
        const float4 v = src[i];
        ushort4 o;
        uint32_t u;
        u = __float_as_uint(v.x); u += 0x7FFFu + ((u >> 16) & 1u); o.x = (unsigned short)(u >> 16);
        u = __float_as_uint(v.y); u += 0x7FFFu + ((u >> 16) & 1u); o.y = (unsigned short)(u >> 16);
        u = __float_as_uint(v.z); u += 0x7FFFu + ((u >> 16) & 1u); o.z = (unsigned short)(u >> 16);
        u = __float_as_uint(v.w); u += 0x7FFFu + ((u >> 16) & 1u); o.w = (unsigned short)(u >> 16);
        dst[i] = o;
    }
}

// ---------------------------------------------------------------------------
// Gather: one wave per item, ONE bf16 row (256B) per wave instruction —
// the shape that measured the best atom rate (R1). lane l holds uint32 =
// bf16 cols [2l, 2l+1]. All 64 token ids preloaded in one wave load and
// broadcast via shfl. Unroll 32 -> 32 dword gathers in flight per wave.
// ---------------------------------------------------------------------------
__global__ __launch_bounds__(256, 4) void avg_gather_bf16_kernel(
    const int*      __restrict__ ids,      // [N_ITEMS]
    const int*      __restrict__ tokens,   // [N_I, PAD_LEN]
    const float*    __restrict__ lens,     // [N_I]
    const uint32_t* __restrict__ emb16,    // [VOCAB, 64] bf16-pairs
    float*          __restrict__ out)      // [N_ITEMS, DD]
{
    const int lane = threadIdx.x & 63;
    const int wave = threadIdx.x >> 6;        // 0..3
    const int item = blockIdx.x * 4 + wave;   // 0..4095

    const int id  = ids[item];                        // wave-uniform
    const int tok = tokens[id * PAD_LEN + lane];      // all 64 slots, one load

    float ax = 0.f, ay = 0.f;

    #pragma unroll 32
    for (int k = 0; k < PAD_LEN; ++k) {
        const int t = __shfl(tok, k, 64);             // slot k's token id
        const uint32_t u = emb16[(size_t)(unsigned)t * 64u + (unsigned)lane];
        ax += __uint_as_float(u << 16);               // col 2*lane   (low bf16)
        ay += __uint_as_float(u & 0xFFFF0000u);       // col 2*lane+1 (high bf16)
    }

    const float inv_len = 1.0f / lens[id];
    float2 r;
    r.x = ax * inv_len;
    r.y = ay * inv_len;
    *reinterpret_cast<float2*>(out + (size_t)item * DD + lane * 2) = r;
}

// ---------------------------------------------------------------------------
// Fallback (ws too small): f32 gather, one wave per item, float2 lanes (R1).
// ---------------------------------------------------------------------------
__global__ __launch_bounds__(256) void avg_gather_f32_kernel(
    const int*   __restrict__ ids,
    const int*   __restrict__ tokens,
    const float* __restrict__ lens,
    const float* __restrict__ emb,
    float*       __restrict__ out)
{
    const int lane = threadIdx.x & 63;
    const int wave = threadIdx.x >> 6;
    const int item = blockIdx.x * 4 + wave;

    const int   id      = ids[item];
    const float inv_len = 1.0f / lens[id];
    const int*  trow    = tokens + id * PAD_LEN;

    float accx = 0.0f, accy = 0.0f;
    #pragma unroll 8
    for (int k = 0; k < PAD_LEN; ++k) {
        const int t = trow[k];
        const float2 e =
            *reinterpret_cast<const float2*>(emb + (size_t)t * DD + lane * 2);
        accx += e.x;
        accy += e.y;
    }
    float2 r;
    r.x = accx * inv_len;
    r.y = accy * inv_len;
    *reinterpret_cast<float2*>(out + (size_t)item * DD + lane * 2) = r;
}

extern "C" void kernel_launch(void* const* d_in, const int* in_sizes, int n_in,
                              void* d_out, int out_size, void* d_ws, size_t ws_size,
                              hipStream_t stream) {
    const int*   ids    = (const int*)  d_in[0];
    const int*   tokens = (const int*)  d_in[1];
    const float* lens   = (const float*)d_in[2];
    const float* emb    = (const float*)d_in[3];
    float*       out    = (float*)d_out;

    const size_t need = (size_t)VOCAB * DD * sizeof(unsigned short);  // 12.8 MB

    if (ws_size >= need) {
        cvt_bf16_kernel<<<N4 / 512, 256, 0, stream>>>(   // 3125 blocks
            (const float4*)emb, (ushort4*)d_ws);
        avg_gather_bf16_kernel<<<N_ITEMS / 4, 256, 0, stream>>>(
            ids, tokens, lens, (const uint32_t*)d_ws, out);
    } else {
        avg_gather_f32_kernel<<<N_ITEMS / 4, 256, 0, stream>>>(
            ids, tokens, lens, emb, out);
    }
}